// Round 10
// baseline (194.909 us; speedup 1.0000x reference)
//
#include <hip/hip_runtime.h>
#include <hip/hip_bf16.h>

#define B_ 4
#define S_ 1024
#define D_ 1024
#define H_ 16
#define HD_ 64
#define M_ (B_*S_)
#define NT_ (S_/64)   // 16 k/v tiles

typedef __attribute__((ext_vector_type(8))) short bf16x8;
typedef __attribute__((ext_vector_type(8))) unsigned short u16x8;
typedef __attribute__((ext_vector_type(4))) float f32x4;

typedef __attribute__((address_space(1))) const unsigned int g_uint;
typedef __attribute__((address_space(3))) unsigned int l_uint;

__device__ __forceinline__ unsigned short f2bf(float f) {
  unsigned int x = __builtin_bit_cast(unsigned int, f);
  unsigned int r = (x + 0x7fffu + ((x >> 16) & 1u)) >> 16;
  return (unsigned short)r;
}
__device__ __forceinline__ float bf2f(unsigned short u) {
  unsigned int x = ((unsigned int)u) << 16;
  return __builtin_bit_cast(float, x);
}
__device__ __forceinline__ unsigned int cvtpk(float lo, float hi) {
  unsigned int r;
  asm("v_cvt_pk_bf16_f32 %0, %1, %2" : "=v"(r) : "v"(lo), "v"(hi));
  return r;
}
__device__ __forceinline__ void load_lds16(const ushort* g, ushort* l) {
  __builtin_amdgcn_global_load_lds((g_uint*)g, (l_uint*)l, 16, 0, 0);
}
__device__ __forceinline__ void store_nt(float* p, f32x4 v) {
  __builtin_nontemporal_store(v, (f32x4*)p);
}

// ---------------- fused fp32 -> bf16 convert ----------------
__global__ void cvt3(const float* __restrict__ q, const float* __restrict__ k,
                     const float* __restrict__ v, ushort* __restrict__ qo,
                     ushort* __restrict__ ko, ushort* __restrict__ vo) {
  const float* s; ushort* d;
  switch (blockIdx.y) {
    case 0: s = q; d = qo; break;
    case 1: s = k; d = ko; break;
    default: s = v; d = vo; break;
  }
  int n4 = (M_ * D_) / 4;
  for (int i = blockIdx.x * blockDim.x + threadIdx.x; i < n4; i += gridDim.x * blockDim.x) {
    float4 x = reinterpret_cast<const float4*>(s)[i];
    ushort4 o;
    o.x = f2bf(x.x); o.y = f2bf(x.y); o.z = f2bf(x.z); o.w = f2bf(x.w);
    reinterpret_cast<ushort4*>(d)[i] = o;
  }
}

// ---------------- fused W -> W^T bf16 ----------------
__global__ void tr4(const float* __restrict__ Wq, const float* __restrict__ Wk,
                    const float* __restrict__ Wv, const float* __restrict__ Wo,
                    ushort* __restrict__ q, ushort* __restrict__ k,
                    ushort* __restrict__ v, ushort* __restrict__ o) {
  const float* W; ushort* WT;
  switch (blockIdx.z) {
    case 0: W = Wq; WT = q; break;
    case 1: W = Wk; WT = k; break;
    case 2: W = Wv; WT = v; break;
    default: W = Wo; WT = o; break;
  }
  __shared__ float tile[32][33];
  int tx = threadIdx.x & 31, ty = threadIdx.x >> 5;
  int bx = blockIdx.x * 32, by = blockIdx.y * 32;
  for (int r = 0; r < 32; r += 8)
    tile[ty + r][tx] = W[(size_t)(by + ty + r) * D_ + bx + tx];
  __syncthreads();
  for (int r = 0; r < 32; r += 8)
    WT[(size_t)(bx + ty + r) * D_ + by + tx] = f2bf(tile[tx][ty + r]);
}

// ---------------- bf16 MFMA GEMM: C[128,128] = A[M,K]*Bt[N,K]^T + bias ----------------
template <int BF16OUT>
__device__ __forceinline__ void gemm_body(const ushort* __restrict__ A,
                                          const ushort* __restrict__ Bt,
                                          const float* __restrict__ bias,
                                          void* __restrict__ Cp,
                                          int bm, int bn, int N, int K) {
  __shared__ ushort Al[128 * 64];
  __shared__ ushort Bl[128 * 64];
  const int tid = threadIdx.x;
  const int wave = tid >> 6, lane = tid & 63;
  const int r0 = lane & 15, kq = lane >> 4;
  const int wr = wave >> 1, wc = wave & 1;
  const int sl = lane >> 3;
  const int sc8 = ((lane & 7) ^ sl) * 8;   // swizzled source col (ushorts)
  f32x4 zero = {0.f, 0.f, 0.f, 0.f};
  f32x4 acc[4][4];
#pragma unroll
  for (int m = 0; m < 4; ++m)
#pragma unroll
    for (int n = 0; n < 4; ++n) acc[m][n] = zero;

  for (int kt = 0; kt < K; kt += 64) {
    __syncthreads();
#pragma unroll
    for (int i = 0; i < 4; ++i) {
      int c = wave * 4 + i;
      load_lds16(A  + (size_t)(bm + c * 8 + sl) * K + kt + sc8, &Al[c * 512]);
      load_lds16(Bt + (size_t)(bn + c * 8 + sl) * K + kt + sc8, &Bl[c * 512]);
    }
    __syncthreads();
#pragma unroll
    for (int kk = 0; kk < 2; ++kk) {
      bf16x8 a[4], b[4];
#pragma unroll
      for (int m = 0; m < 4; ++m)
        a[m] = *(const bf16x8*)&Al[(wr * 64 + m * 16 + r0) * 64 + (((kk * 4 + kq) ^ (r0 & 7)) * 8)];
#pragma unroll
      for (int n = 0; n < 4; ++n)
        b[n] = *(const bf16x8*)&Bl[(wc * 64 + n * 16 + r0) * 64 + (((kk * 4 + kq) ^ (r0 & 7)) * 8)];
#pragma unroll
      for (int m = 0; m < 4; ++m)
#pragma unroll
        for (int n = 0; n < 4; ++n)
          acc[m][n] = __builtin_amdgcn_mfma_f32_16x16x32_bf16(a[m], b[n], acc[m][n], 0, 0, 0);
    }
  }

#pragma unroll
  for (int m = 0; m < 4; ++m) {
#pragma unroll
    for (int n = 0; n < 4; ++n) {
      int col = bn + wc * 64 + n * 16 + r0;
      float bv = bias[col];
#pragma unroll
      for (int j = 0; j < 4; ++j) {
        int row = bm + wr * 64 + m * 16 + kq * 4 + j;
        float v = acc[m][n][j] + bv;
        if (BF16OUT) ((ushort*)Cp)[(size_t)row * N + col] = f2bf(v);
        else __builtin_nontemporal_store(v, &((float*)Cp)[(size_t)row * N + col]);
      }
    }
  }
}

__global__ __launch_bounds__(256) void gemm_qkv(const ushort* __restrict__ qa,
                                                const ushort* __restrict__ ka,
                                                const ushort* __restrict__ va,
                                                const ushort* __restrict__ WqT,
                                                const ushort* __restrict__ WkT,
                                                const ushort* __restrict__ WvT,
                                                const float* __restrict__ bq,
                                                const float* __restrict__ bk,
                                                const float* __restrict__ bv,
                                                ushort* __restrict__ Qo,
                                                ushort* __restrict__ Ko,
                                                ushort* __restrict__ Vo) {
  const ushort* A; const ushort* Bt; const float* bias; ushort* C;
  switch (blockIdx.z) {
    case 0: A = qa; Bt = WqT; bias = bq; C = Qo; break;
    case 1: A = ka; Bt = WkT; bias = bk; C = Ko; break;
    default: A = va; Bt = WvT; bias = bv; C = Vo; break;
  }
  gemm_body<1>(A, Bt, bias, C, blockIdx.x * 128, blockIdx.y * 128, D_, D_);
}

__global__ __launch_bounds__(256) void gemm_out(const ushort* __restrict__ A,
                                                const ushort* __restrict__ Bt,
                                                const float* __restrict__ bias,
                                                float* __restrict__ C) {
  gemm_body<0>(A, Bt, bias, C, blockIdx.x * 128, blockIdx.y * 128, D_, D_);
}

// ---------------- fused attention (swapped QK^T: lane owns one q-row) ----------------
// grid 1024: id&63 = (b,h) -> XCD-local K/V panel; qt = 15-(id>>6) heavy-first.
// LDS 40KB -> 4 blocks/CU. All d_out stores non-temporal (never re-read).
__global__ __launch_bounds__(256) void attn_fused(const ushort* __restrict__ Qb,
                                                  const ushort* __restrict__ Kb,
                                                  const ushort* __restrict__ Vb,
                                                  float* __restrict__ wout,
                                                  ushort* __restrict__ ctx) {
  const int id = blockIdx.x;
  const int bh = id & 63;
  const int b = bh >> 4, h = bh & 15;
  const int qt = NT_ - 1 - (id >> 6);
  const int tid = threadIdx.x, wave = tid >> 6, lane = tid & 63;
  const int r0 = lane & 15, kq = lane >> 4;
  const int sl = lane >> 3;
  const int sc8 = ((lane & 7) ^ sl) * 8;
  __shared__ ushort Kt[2][64 * 64];   // dbuf, both-sides swizzle slot^=(row&7)
  __shared__ ushort Vt[2][64 * 64];   // dbuf, V^T [d][k], col^=(d&7)<<3
  __shared__ ushort Wl[4][16 * 64];   // per-wave P tile [qrow16][k64], 8B-slot swz
  const size_t bh_off = ((size_t)(b * S_)) * D_ + (size_t)h * 64;
  float* wbase = wout + (size_t)bh * S_ * S_;
  const float KSC = 0.18033688011f;   // 0.125 * log2(e)

  // ---- zero the fully-masked region FIRST: fills the write pipe while
  // heavy blocks run pass-1 (which issues no stores). nt: never re-read.
  {
    int col0 = (qt + 1) * 64;
    int nf4 = (S_ - col0) >> 2;
    int row = tid >> 2, c = tid & 3;
    f32x4 z4 = {0.f, 0.f, 0.f, 0.f};
    float* rp = &wbase[(size_t)(qt * 64 + row) * S_];
    for (int i = c; i < nf4; i += 4) store_nt(&rp[col0 + i * 4], z4);
  }

  // Q fragments straight from global; this lane's q-row = qglob
  const ushort* Qg = Qb + bh_off + (size_t)(qt * 64 + wave * 16 + r0) * D_ + kq * 8;
  bf16x8 qa0 = *(const bf16x8*)Qg;
  bf16x8 qa1 = *(const bf16x8*)(Qg + 32);
  const int qglob = qt * 64 + wave * 16 + r0;

  auto stage_K = [&](int buf, int vb) {
    const ushort* Kg = Kb + bh_off + (size_t)(vb * 64) * D_;
#pragma unroll
    for (int i = 0; i < 2; ++i) {
      int c = wave * 2 + i;
      load_lds16(Kg + (size_t)(c * 8 + sl) * D_ + sc8, &Kt[buf][c * 512]);
    }
  };

  // ---- pass 1: row sums. swapped mfma(K,Q): sc[j] = S[k=jt*16+kq*4+j][q=r0]
  int cur = 0;
  stage_K(0, 0);
  float p0 = 0.f, p1 = 0.f, p2 = 0.f, p3 = 0.f;
  for (int vb = 0; vb <= qt; ++vb) {
    // zero-fill stores are still in flight; count them out is impossible per-lane
    // (variable count), so retire everything the first iteration only.
    asm volatile("s_waitcnt vmcnt(0)" ::: "memory");
    __builtin_amdgcn_s_barrier();
    if (vb < qt) stage_K(cur ^ 1, vb + 1);
    const bool diag = (vb == qt);
#pragma unroll
    for (int jt = 0; jt < 4; ++jt) {
      int krow = jt * 16 + r0;
      bf16x8 kb0 = *(const bf16x8*)&Kt[cur][krow * 64 + ((kq ^ (r0 & 7)) * 8)];
      bf16x8 kb1 = *(const bf16x8*)&Kt[cur][krow * 64 + (((4 + kq) ^ (r0 & 7)) * 8)];
      f32x4 sc = {0.f, 0.f, 0.f, 0.f};
      sc = __builtin_amdgcn_mfma_f32_16x16x32_bf16(kb0, qa0, sc, 0, 0, 0);
      sc = __builtin_amdgcn_mfma_f32_16x16x32_bf16(kb1, qa1, sc, 0, 0, 0);
      int k0 = vb * 64 + jt * 16 + kq * 4;
      p0 += (diag && k0 + 0 > qglob) ? 0.f : exp2f(sc[0] * KSC);
      p1 += (diag && k0 + 1 > qglob) ? 0.f : exp2f(sc[1] * KSC);
      p2 += (diag && k0 + 2 > qglob) ? 0.f : exp2f(sc[2] * KSC);
      p3 += (diag && k0 + 3 > qglob) ? 0.f : exp2f(sc[3] * KSC);
    }
    cur ^= 1;
  }
  float ssum = (p0 + p1) + (p2 + p3);
  ssum += __shfl_xor(ssum, 16, 64);
  ssum += __shfl_xor(ssum, 32, 64);
  const float rs = 1.f / ssum;   // reciprocal row-sum for q-row qglob

  f32x4 zero = {0.f, 0.f, 0.f, 0.f};
  f32x4 cacc[4];
#pragma unroll
  for (int nt = 0; nt < 4; ++nt) cacc[nt] = zero;

  // ---- pass 2: weights out (from regs, nt) + PV
  __syncthreads();  // pass1 -> pass2 LDS buffer reuse guard
  uint4 vr[2];
  auto vload = [&](int vb) {
    const ushort* Vg = Vb + bh_off + (size_t)(vb * 64) * D_;
    vr[0] = *(const uint4*)&Vg[(size_t)lane * D_ + (size_t)(wave * 2 + 0) * 8];
    vr[1] = *(const uint4*)&Vg[(size_t)lane * D_ + (size_t)(wave * 2 + 1) * 8];
  };
  auto vwrite = [&](int buf) {
#pragma unroll
    for (int it = 0; it < 2; ++it) {
      int seg = wave * 2 + it;
      ushort tmp[8];
      *(uint4*)tmp = vr[it];
#pragma unroll
      for (int e = 0; e < 8; ++e) Vt[buf][(seg * 8 + e) * 64 + (lane ^ (e << 3))] = tmp[e];
    }
  };
  cur = 0;
  stage_K(0, 0);
  vload(0);
  vwrite(0);
  for (int vb = 0; vb <= qt; ++vb) {
    // loads (4) issued before prev tile's 4 weight stores -> vmcnt(4) retires
    // exactly the loads; stores stay in flight across the barrier.
    if (vb == 0) asm volatile("s_waitcnt vmcnt(0) lgkmcnt(0)" ::: "memory");
    else         asm volatile("s_waitcnt vmcnt(4) lgkmcnt(0)" ::: "memory");
    __builtin_amdgcn_s_barrier();
    if (vb < qt) { stage_K(cur ^ 1, vb + 1); vload(vb + 1); }
    const bool diag = (vb == qt);
#pragma unroll
    for (int jt = 0; jt < 4; ++jt) {
      int krow = jt * 16 + r0;
      bf16x8 kb0 = *(const bf16x8*)&Kt[cur][krow * 64 + ((kq ^ (r0 & 7)) * 8)];
      bf16x8 kb1 = *(const bf16x8*)&Kt[cur][krow * 64 + (((4 + kq) ^ (r0 & 7)) * 8)];
      f32x4 sc = {0.f, 0.f, 0.f, 0.f};
      sc = __builtin_amdgcn_mfma_f32_16x16x32_bf16(kb0, qa0, sc, 0, 0, 0);
      sc = __builtin_amdgcn_mfma_f32_16x16x32_bf16(kb1, qa1, sc, 0, 0, 0);
      int k0 = vb * 64 + jt * 16 + kq * 4;
      float e0 = (diag && k0 + 0 > qglob) ? 0.f : exp2f(sc[0] * KSC);
      float e1 = (diag && k0 + 1 > qglob) ? 0.f : exp2f(sc[1] * KSC);
      float e2 = (diag && k0 + 2 > qglob) ? 0.f : exp2f(sc[2] * KSC);
      float e3 = (diag && k0 + 3 > qglob) ? 0.f : exp2f(sc[3] * KSC);
      // packed bf16 quad -> Wl (one ds_write_b64), 8B-slot swizzle s^=(r0&3)<<2
      uint2 pk;
      pk.x = cvtpk(e0, e1);
      pk.y = cvtpk(e2, e3);
      int s = (4 * jt + kq) ^ ((r0 & 3) << 2);
      *(uint2*)&Wl[wave][r0 * 64 + s * 4] = pk;
      // normalized fp32 weights straight from registers (one nt dwordx4)
      f32x4 o = {e0 * rs, e1 * rs, e2 * rs, e3 * rs};
      store_nt(&wbase[(size_t)qglob * S_ + k0], o);
    }
    // PV (unnormalized; scaled at the end)
#pragma unroll
    for (int ks = 0; ks < 2; ++ks) {
      int sB = (8 * ks + 2 * kq) ^ ((r0 & 3) << 2);
      bf16x8 af = *(const bf16x8*)&Wl[wave][r0 * 64 + sB * 4];
#pragma unroll
      for (int nt = 0; nt < 4; ++nt) {
        bf16x8 vf = *(const bf16x8*)&Vt[cur][(nt * 16 + r0) * 64 + (((ks * 4 + kq) ^ (r0 & 7)) * 8)];
        cacc[nt] = __builtin_amdgcn_mfma_f32_16x16x32_bf16(af, vf, cacc[nt], 0, 0, 0);
      }
    }
    if (vb < qt) vwrite(cur ^ 1);  // ds_write next V tile (loads landed during compute)
    cur ^= 1;
  }

  // ---- context out (scaled; rs for q-row kq*4+j fetched from lane kq*4+j)
  {
    float rsj[4];
#pragma unroll
    for (int j = 0; j < 4; ++j) rsj[j] = __shfl(rs, kq * 4 + j, 64);
    ushort* cg = ctx + ((size_t)(b * S_ + qt * 64 + wave * 16 + kq * 4)) * D_ + h * 64;
#pragma unroll
    for (int nt = 0; nt < 4; ++nt)
#pragma unroll
      for (int j = 0; j < 4; ++j)
        cg[(size_t)j * D_ + nt * 16 + r0] = f2bf(cacc[nt][j] * rsj[j]);
  }
}

extern "C" void kernel_launch(void* const* d_in, const int* in_sizes, int n_in,
                              void* d_out, int out_size, void* d_ws, size_t ws_size,
                              hipStream_t stream) {
  const float* q    = (const float*)d_in[0];
  const float* k    = (const float*)d_in[1];
  const float* v    = (const float*)d_in[2];
  const float* Wq   = (const float*)d_in[4];
  const float* bq   = (const float*)d_in[5];
  const float* Wk   = (const float*)d_in[6];
  const float* bk   = (const float*)d_in[7];
  const float* Wv   = (const float*)d_in[8];
  const float* bv   = (const float*)d_in[9];
  const float* Wo   = (const float*)d_in[10];
  const float* bo   = (const float*)d_in[11];

  char* ws = (char*)d_ws;
  const size_t MB = 1024 * 1024;
  ushort* q_bf   = (ushort*)(ws + 0 * MB);
  ushort* k_bf   = (ushort*)(ws + 8 * MB);
  ushort* v_bf   = (ushort*)(ws + 16 * MB);
  ushort* WqT    = (ushort*)(ws + 24 * MB);
  ushort* WkT    = (ushort*)(ws + 26 * MB);
  ushort* WvT    = (ushort*)(ws + 28 * MB);
  ushort* WoT    = (ushort*)(ws + 30 * MB);
  ushort* Q_bf   = (ushort*)(ws + 32 * MB);
  ushort* K_bf   = (ushort*)(ws + 40 * MB);
  ushort* V_bf   = (ushort*)(ws + 48 * MB);
  ushort* ctx_bf = (ushort*)(ws + 56 * MB);

  float* out  = (float*)d_out;
  float* wout = out + (size_t)M_ * D_;

  cvt3<<<dim3(2048, 3), 256, 0, stream>>>(q, k, v, q_bf, k_bf, v_bf);
  tr4<<<dim3(32, 32, 4), 256, 0, stream>>>(Wq, Wk, Wv, Wo, WqT, WkT, WvT, WoT);
  gemm_qkv<<<dim3(M_ / 128, D_ / 128, 3), 256, 0, stream>>>(
      q_bf, k_bf, v_bf, WqT, WkT, WvT, bq, bk, bv, Q_bf, K_bf, V_bf);
  attn_fused<<<dim3(1024), 256, 0, stream>>>(Q_bf, K_bf, V_bf, wout, ctx_bf);
  gemm_out<<<dim3(M_ / 128, D_ / 128), 256, 0, stream>>>(ctx_bf, WoT, bo, out);
}

// Round 11
// 173.395 us; speedup vs baseline: 1.1241x; 1.1241x over previous
//
#include <hip/hip_runtime.h>
#include <hip/hip_bf16.h>

#define B_ 4
#define S_ 1024
#define D_ 1024
#define H_ 16
#define HD_ 64
#define M_ (B_*S_)
#define NT_ (S_/64)   // 16 k/v tiles

typedef __attribute__((ext_vector_type(8))) short bf16x8;
typedef __attribute__((ext_vector_type(8))) unsigned short u16x8;
typedef __attribute__((ext_vector_type(4))) float f32x4;

typedef __attribute__((address_space(1))) const unsigned int g_uint;
typedef __attribute__((address_space(3))) unsigned int l_uint;

__device__ __forceinline__ unsigned short f2bf(float f) {
  unsigned int x = __builtin_bit_cast(unsigned int, f);
  unsigned int r = (x + 0x7fffu + ((x >> 16) & 1u)) >> 16;
  return (unsigned short)r;
}
__device__ __forceinline__ float bf2f(unsigned short u) {
  unsigned int x = ((unsigned int)u) << 16;
  return __builtin_bit_cast(float, x);
}
__device__ __forceinline__ unsigned int cvtpk(float lo, float hi) {
  unsigned int r;
  asm("v_cvt_pk_bf16_f32 %0, %1, %2" : "=v"(r) : "v"(lo), "v"(hi));
  return r;
}
__device__ __forceinline__ void load_lds16(const ushort* g, ushort* l) {
  __builtin_amdgcn_global_load_lds((g_uint*)g, (l_uint*)l, 16, 0, 0);
}

// ---------------- fused fp32 -> bf16 convert ----------------
__global__ void cvt3(const float* __restrict__ q, const float* __restrict__ k,
                     const float* __restrict__ v, ushort* __restrict__ qo,
                     ushort* __restrict__ ko, ushort* __restrict__ vo) {
  const float* s; ushort* d;
  switch (blockIdx.y) {
    case 0: s = q; d = qo; break;
    case 1: s = k; d = ko; break;
    default: s = v; d = vo; break;
  }
  int n4 = (M_ * D_) / 4;
  for (int i = blockIdx.x * blockDim.x + threadIdx.x; i < n4; i += gridDim.x * blockDim.x) {
    float4 x = reinterpret_cast<const float4*>(s)[i];
    ushort4 o;
    o.x = f2bf(x.x); o.y = f2bf(x.y); o.z = f2bf(x.z); o.w = f2bf(x.w);
    reinterpret_cast<ushort4*>(d)[i] = o;
  }
}

// ---------------- fused W -> W^T bf16 ----------------
__global__ void tr4(const float* __restrict__ Wq, const float* __restrict__ Wk,
                    const float* __restrict__ Wv, const float* __restrict__ Wo,
                    ushort* __restrict__ q, ushort* __restrict__ k,
                    ushort* __restrict__ v, ushort* __restrict__ o) {
  const float* W; ushort* WT;
  switch (blockIdx.z) {
    case 0: W = Wq; WT = q; break;
    case 1: W = Wk; WT = k; break;
    case 2: W = Wv; WT = v; break;
    default: W = Wo; WT = o; break;
  }
  __shared__ float tile[32][33];
  int tx = threadIdx.x & 31, ty = threadIdx.x >> 5;
  int bx = blockIdx.x * 32, by = blockIdx.y * 32;
  for (int r = 0; r < 32; r += 8)
    tile[ty + r][tx] = W[(size_t)(by + ty + r) * D_ + bx + tx];
  __syncthreads();
  for (int r = 0; r < 32; r += 8)
    WT[(size_t)(bx + ty + r) * D_ + by + tx] = f2bf(tile[tx][ty + r]);
}

// ---------------- bf16 MFMA GEMM: C[128,128] = A[M,K]*Bt[N,K]^T + bias ----------------
template <int BF16OUT>
__device__ __forceinline__ void gemm_body(const ushort* __restrict__ A,
                                          const ushort* __restrict__ Bt,
                                          const float* __restrict__ bias,
                                          void* __restrict__ Cp,
                                          int bm, int bn, int N, int K) {
  __shared__ ushort Al[128 * 64];
  __shared__ ushort Bl[128 * 64];
  const int tid = threadIdx.x;
  const int wave = tid >> 6, lane = tid & 63;
  const int r0 = lane & 15, kq = lane >> 4;
  const int wr = wave >> 1, wc = wave & 1;
  const int sl = lane >> 3;
  const int sc8 = ((lane & 7) ^ sl) * 8;   // swizzled source col (ushorts)
  f32x4 zero = {0.f, 0.f, 0.f, 0.f};
  f32x4 acc[4][4];
#pragma unroll
  for (int m = 0; m < 4; ++m)
#pragma unroll
    for (int n = 0; n < 4; ++n) acc[m][n] = zero;

  for (int kt = 0; kt < K; kt += 64) {
    __syncthreads();
#pragma unroll
    for (int i = 0; i < 4; ++i) {
      int c = wave * 4 + i;
      load_lds16(A  + (size_t)(bm + c * 8 + sl) * K + kt + sc8, &Al[c * 512]);
      load_lds16(Bt + (size_t)(bn + c * 8 + sl) * K + kt + sc8, &Bl[c * 512]);
    }
    __syncthreads();
#pragma unroll
    for (int kk = 0; kk < 2; ++kk) {
      bf16x8 a[4], b[4];
#pragma unroll
      for (int m = 0; m < 4; ++m)
        a[m] = *(const bf16x8*)&Al[(wr * 64 + m * 16 + r0) * 64 + (((kk * 4 + kq) ^ (r0 & 7)) * 8)];
#pragma unroll
      for (int n = 0; n < 4; ++n)
        b[n] = *(const bf16x8*)&Bl[(wc * 64 + n * 16 + r0) * 64 + (((kk * 4 + kq) ^ (r0 & 7)) * 8)];
#pragma unroll
      for (int m = 0; m < 4; ++m)
#pragma unroll
        for (int n = 0; n < 4; ++n)
          acc[m][n] = __builtin_amdgcn_mfma_f32_16x16x32_bf16(a[m], b[n], acc[m][n], 0, 0, 0);
    }
  }

#pragma unroll
  for (int m = 0; m < 4; ++m) {
#pragma unroll
    for (int n = 0; n < 4; ++n) {
      int col = bn + wc * 64 + n * 16 + r0;
      float bv = bias[col];
#pragma unroll
      for (int j = 0; j < 4; ++j) {
        int row = bm + wr * 64 + m * 16 + kq * 4 + j;
        float v = acc[m][n][j] + bv;
        if (BF16OUT) ((ushort*)Cp)[(size_t)row * N + col] = f2bf(v);
        else         ((float*)Cp)[(size_t)row * N + col] = v;
      }
    }
  }
}

__global__ __launch_bounds__(256) void gemm_qkv(const ushort* __restrict__ qa,
                                                const ushort* __restrict__ ka,
                                                const ushort* __restrict__ va,
                                                const ushort* __restrict__ WqT,
                                                const ushort* __restrict__ WkT,
                                                const ushort* __restrict__ WvT,
                                                const float* __restrict__ bq,
                                                const float* __restrict__ bk,
                                                const float* __restrict__ bv,
                                                ushort* __restrict__ Qo,
                                                ushort* __restrict__ Ko,
                                                ushort* __restrict__ Vo) {
  const ushort* A; const ushort* Bt; const float* bias; ushort* C;
  switch (blockIdx.z) {
    case 0: A = qa; Bt = WqT; bias = bq; C = Qo; break;
    case 1: A = ka; Bt = WkT; bias = bk; C = Ko; break;
    default: A = va; Bt = WvT; bias = bv; C = Vo; break;
  }
  gemm_body<1>(A, Bt, bias, C, blockIdx.x * 128, blockIdx.y * 128, D_, D_);
}

__global__ __launch_bounds__(256) void gemm_out(const ushort* __restrict__ A,
                                                const ushort* __restrict__ Bt,
                                                const float* __restrict__ bias,
                                                float* __restrict__ C) {
  gemm_body<0>(A, Bt, bias, C, blockIdx.x * 128, blockIdx.y * 128, D_, D_);
}

// ---------------- fused attention (swapped QK^T: lane owns one q-row) ----------------
// grid 1024: id&63 = (b,h) -> XCD-local K/V panel; qt = 15-(id>>6) heavy-first.
// LDS 40KB -> 4 blocks/CU. Pass 1 uses a 4-slot K ring (depth-3 prefetch) built
// from the K dbuf + the (idle) V dbuf; pass 2 uses K dbuf + V dbuf as before.
__global__ __launch_bounds__(256) void attn_fused(const ushort* __restrict__ Qb,
                                                  const ushort* __restrict__ Kb,
                                                  const ushort* __restrict__ Vb,
                                                  float* __restrict__ wout,
                                                  ushort* __restrict__ ctx) {
  const int id = blockIdx.x;
  const int bh = id & 63;
  const int b = bh >> 4, h = bh & 15;
  const int qt = NT_ - 1 - (id >> 6);
  const int tid = threadIdx.x, wave = tid >> 6, lane = tid & 63;
  const int r0 = lane & 15, kq = lane >> 4;
  const int sl = lane >> 3;
  const int sc8 = ((lane & 7) ^ sl) * 8;
  __shared__ ushort KV[4][64 * 64];   // slots: pass1 = 4-deep K ring; pass2 = K dbuf(0,1) + V^T dbuf(2,3)
  __shared__ ushort Wl[4][16 * 64];   // per-wave P tile [qrow16][k64], 8B-slot swz
  const size_t bh_off = ((size_t)(b * S_)) * D_ + (size_t)h * 64;
  float* wbase = wout + (size_t)bh * S_ * S_;
  const float KSC = 0.18033688011f;   // 0.125 * log2(e)

  // Q fragments straight from global; this lane's q-row = qglob
  const ushort* Qg = Qb + bh_off + (size_t)(qt * 64 + wave * 16 + r0) * D_ + kq * 8;
  bf16x8 qa0 = *(const bf16x8*)Qg;
  bf16x8 qa1 = *(const bf16x8*)(Qg + 32);
  const int qglob = qt * 64 + wave * 16 + r0;

  auto stage_K = [&](int slot, int vb) {
    const ushort* Kg = Kb + bh_off + (size_t)(vb * 64) * D_;
#pragma unroll
    for (int i = 0; i < 2; ++i) {
      int c = wave * 2 + i;
      load_lds16(Kg + (size_t)(c * 8 + sl) * D_ + sc8, &KV[slot][c * 512]);
    }
  };

  // ---- pass 1: row sums, 4-slot ring, depth-3 prefetch.
  // swapped mfma(K,Q): sc[j] = S[k=jt*16+kq*4+j][q=r0]
  {
    int nst = (qt < 2) ? qt : 2;
    for (int t = 0; t <= nst; ++t) stage_K(t & 3, t);
  }
  float p0 = 0.f, p1 = 0.f, p2 = 0.f, p3 = 0.f;
  for (int vb = 0; vb <= qt; ++vb) {
    int ahead = qt - vb; if (ahead > 2) ahead = 2;   // tiles in flight beyond vb
    if (ahead == 2)      asm volatile("s_waitcnt vmcnt(4)" ::: "memory");
    else if (ahead == 1) asm volatile("s_waitcnt vmcnt(2)" ::: "memory");
    else                 asm volatile("s_waitcnt vmcnt(0)" ::: "memory");
    __builtin_amdgcn_s_barrier();
    if (vb + 3 <= qt) stage_K((vb + 3) & 3, vb + 3);  // refill ring, flies over compute
    const ushort* Kc = KV[vb & 3];
    const bool diag = (vb == qt);
#pragma unroll
    for (int jt = 0; jt < 4; ++jt) {
      int krow = jt * 16 + r0;
      bf16x8 kb0 = *(const bf16x8*)&Kc[krow * 64 + ((kq ^ (r0 & 7)) * 8)];
      bf16x8 kb1 = *(const bf16x8*)&Kc[krow * 64 + (((4 + kq) ^ (r0 & 7)) * 8)];
      f32x4 sc = {0.f, 0.f, 0.f, 0.f};
      sc = __builtin_amdgcn_mfma_f32_16x16x32_bf16(kb0, qa0, sc, 0, 0, 0);
      sc = __builtin_amdgcn_mfma_f32_16x16x32_bf16(kb1, qa1, sc, 0, 0, 0);
      int k0 = vb * 64 + jt * 16 + kq * 4;
      p0 += (diag && k0 + 0 > qglob) ? 0.f : exp2f(sc[0] * KSC);
      p1 += (diag && k0 + 1 > qglob) ? 0.f : exp2f(sc[1] * KSC);
      p2 += (diag && k0 + 2 > qglob) ? 0.f : exp2f(sc[2] * KSC);
      p3 += (diag && k0 + 3 > qglob) ? 0.f : exp2f(sc[3] * KSC);
    }
  }
  float ssum = (p0 + p1) + (p2 + p3);
  ssum += __shfl_xor(ssum, 16, 64);
  ssum += __shfl_xor(ssum, 32, 64);
  const float rs = 1.f / ssum;   // reciprocal row-sum for q-row qglob

  f32x4 zero = {0.f, 0.f, 0.f, 0.f};
  f32x4 cacc[4];
#pragma unroll
  for (int nt = 0; nt < 4; ++nt) cacc[nt] = zero;

  // ---- pass 2: weights out (from regs) + PV
  __syncthreads();  // pass1 -> pass2 LDS buffer reuse guard
  uint4 vr[2];
  auto vload = [&](int vb) {
    const ushort* Vg = Vb + bh_off + (size_t)(vb * 64) * D_;
    vr[0] = *(const uint4*)&Vg[(size_t)lane * D_ + (size_t)(wave * 2 + 0) * 8];
    vr[1] = *(const uint4*)&Vg[(size_t)lane * D_ + (size_t)(wave * 2 + 1) * 8];
  };
  auto vwrite = [&](int buf) {
#pragma unroll
    for (int it = 0; it < 2; ++it) {
      int seg = wave * 2 + it;
      ushort tmp[8];
      *(uint4*)tmp = vr[it];
#pragma unroll
      for (int e = 0; e < 8; ++e) KV[2 + buf][(seg * 8 + e) * 64 + (lane ^ (e << 3))] = tmp[e];
    }
  };
  int cur = 0;
  stage_K(0, 0);
  vload(0);
  vwrite(0);
  for (int vb = 0; vb <= qt; ++vb) {
    // loads (4) issued before prev tile's 4 weight stores -> vmcnt(4) retires
    // exactly the loads; stores stay in flight across the barrier.
    if (vb == 0) asm volatile("s_waitcnt vmcnt(0) lgkmcnt(0)" ::: "memory");
    else         asm volatile("s_waitcnt vmcnt(4) lgkmcnt(0)" ::: "memory");
    __builtin_amdgcn_s_barrier();
    if (vb < qt) { stage_K(cur ^ 1, vb + 1); vload(vb + 1); }
    const ushort* Kc = KV[cur];
    const ushort* Vc = KV[2 + cur];
    const bool diag = (vb == qt);
#pragma unroll
    for (int jt = 0; jt < 4; ++jt) {
      int krow = jt * 16 + r0;
      bf16x8 kb0 = *(const bf16x8*)&Kc[krow * 64 + ((kq ^ (r0 & 7)) * 8)];
      bf16x8 kb1 = *(const bf16x8*)&Kc[krow * 64 + (((4 + kq) ^ (r0 & 7)) * 8)];
      f32x4 sc = {0.f, 0.f, 0.f, 0.f};
      sc = __builtin_amdgcn_mfma_f32_16x16x32_bf16(kb0, qa0, sc, 0, 0, 0);
      sc = __builtin_amdgcn_mfma_f32_16x16x32_bf16(kb1, qa1, sc, 0, 0, 0);
      int k0 = vb * 64 + jt * 16 + kq * 4;
      float e0 = (diag && k0 + 0 > qglob) ? 0.f : exp2f(sc[0] * KSC);
      float e1 = (diag && k0 + 1 > qglob) ? 0.f : exp2f(sc[1] * KSC);
      float e2 = (diag && k0 + 2 > qglob) ? 0.f : exp2f(sc[2] * KSC);
      float e3 = (diag && k0 + 3 > qglob) ? 0.f : exp2f(sc[3] * KSC);
      // packed bf16 quad -> Wl (one ds_write_b64), 8B-slot swizzle s^=(r0&3)<<2
      uint2 pk;
      pk.x = cvtpk(e0, e1);
      pk.y = cvtpk(e2, e3);
      int s = (4 * jt + kq) ^ ((r0 & 3) << 2);
      *(uint2*)&Wl[wave][r0 * 64 + s * 4] = pk;
      // normalized fp32 weights straight from registers (one dwordx4)
      f32x4 o = {e0 * rs, e1 * rs, e2 * rs, e3 * rs};
      *(f32x4*)&wbase[(size_t)qglob * S_ + k0] = o;
    }
    // PV (unnormalized; scaled at the end)
#pragma unroll
    for (int ks = 0; ks < 2; ++ks) {
      int sB = (8 * ks + 2 * kq) ^ ((r0 & 3) << 2);
      bf16x8 af = *(const bf16x8*)&Wl[wave][r0 * 64 + sB * 4];
#pragma unroll
      for (int nt = 0; nt < 4; ++nt) {
        bf16x8 vf = *(const bf16x8*)&Vc[(nt * 16 + r0) * 64 + (((ks * 4 + kq) ^ (r0 & 7)) * 8)];
        cacc[nt] = __builtin_amdgcn_mfma_f32_16x16x32_bf16(af, vf, cacc[nt], 0, 0, 0);
      }
    }
    if (vb < qt) vwrite(cur ^ 1);  // ds_write next V tile (loads landed during compute)
    cur ^= 1;
  }

  // ---- zero the fully-masked region
  {
    int col0 = (qt + 1) * 64;
    int nf4 = (S_ - col0) >> 2;
    int row = tid >> 2, c = tid & 3;
    f32x4 z4 = {0.f, 0.f, 0.f, 0.f};
    float* rp = &wbase[(size_t)(qt * 64 + row) * S_];
    for (int i = c; i < nf4; i += 4) *(f32x4*)&rp[col0 + i * 4] = z4;
  }

  // ---- context out (scaled; rs for q-row kq*4+j fetched from lane kq*4+j)
  {
    float rsj[4];
#pragma unroll
    for (int j = 0; j < 4; ++j) rsj[j] = __shfl(rs, kq * 4 + j, 64);
    ushort* cg = ctx + ((size_t)(b * S_ + qt * 64 + wave * 16 + kq * 4)) * D_ + h * 64;
#pragma unroll
    for (int nt = 0; nt < 4; ++nt)
#pragma unroll
      for (int j = 0; j < 4; ++j)
        cg[(size_t)j * D_ + nt * 16 + r0] = f2bf(cacc[nt][j] * rsj[j]);
  }
}

extern "C" void kernel_launch(void* const* d_in, const int* in_sizes, int n_in,
                              void* d_out, int out_size, void* d_ws, size_t ws_size,
                              hipStream_t stream) {
  const float* q    = (const float*)d_in[0];
  const float* k    = (const float*)d_in[1];
  const float* v    = (const float*)d_in[2];
  const float* Wq   = (const float*)d_in[4];
  const float* bq   = (const float*)d_in[5];
  const float* Wk   = (const float*)d_in[6];
  const float* bk   = (const float*)d_in[7];
  const float* Wv   = (const float*)d_in[8];
  const float* bv   = (const float*)d_in[9];
  const float* Wo   = (const float*)d_in[10];
  const float* bo   = (const float*)d_in[11];

  char* ws = (char*)d_ws;
  const size_t MB = 1024 * 1024;
  ushort* q_bf   = (ushort*)(ws + 0 * MB);
  ushort* k_bf   = (ushort*)(ws + 8 * MB);
  ushort* v_bf   = (ushort*)(ws + 16 * MB);
  ushort* WqT    = (ushort*)(ws + 24 * MB);
  ushort* WkT    = (ushort*)(ws + 26 * MB);
  ushort* WvT    = (ushort*)(ws + 28 * MB);
  ushort* WoT    = (ushort*)(ws + 30 * MB);
  ushort* Q_bf   = (ushort*)(ws + 32 * MB);
  ushort* K_bf   = (ushort*)(ws + 40 * MB);
  ushort* V_bf   = (ushort*)(ws + 48 * MB);
  ushort* ctx_bf = (ushort*)(ws + 56 * MB);

  float* out  = (float*)d_out;
  float* wout = out + (size_t)M_ * D_;

  cvt3<<<dim3(2048, 3), 256, 0, stream>>>(q, k, v, q_bf, k_bf, v_bf);
  tr4<<<dim3(32, 32, 4), 256, 0, stream>>>(Wq, Wk, Wv, Wo, WqT, WkT, WvT, WoT);
  gemm_qkv<<<dim3(M_ / 128, D_ / 128, 3), 256, 0, stream>>>(
      q_bf, k_bf, v_bf, WqT, WkT, WvT, bq, bk, bv, Q_bf, K_bf, V_bf);
  attn_fused<<<dim3(1024), 256, 0, stream>>>(Q_bf, K_bf, V_bf, wout, ctx_bf);
  gemm_out<<<dim3(M_ / 128, D_ / 128), 256, 0, stream>>>(ctx_bf, WoT, bo, out);
}

// Round 12
// 165.416 us; speedup vs baseline: 1.1783x; 1.0482x over previous
//
#include <hip/hip_runtime.h>
#include <hip/hip_bf16.h>

#define B_ 4
#define S_ 1024
#define D_ 1024
#define H_ 16
#define HD_ 64
#define M_ (B_*S_)
#define NT_ (S_/64)   // 16 k/v tiles

typedef __attribute__((ext_vector_type(8))) short bf16x8;
typedef __attribute__((ext_vector_type(8))) unsigned short u16x8;
typedef __attribute__((ext_vector_type(4))) float f32x4;

typedef __attribute__((address_space(1))) const unsigned int g_uint;
typedef __attribute__((address_space(3))) unsigned int l_uint;

__device__ __forceinline__ unsigned short f2bf(float f) {
  unsigned int x = __builtin_bit_cast(unsigned int, f);
  unsigned int r = (x + 0x7fffu + ((x >> 16) & 1u)) >> 16;
  return (unsigned short)r;
}
__device__ __forceinline__ float bf2f(unsigned short u) {
  unsigned int x = ((unsigned int)u) << 16;
  return __builtin_bit_cast(float, x);
}
__device__ __forceinline__ unsigned int cvtpk(float lo, float hi) {
  unsigned int r;
  asm("v_cvt_pk_bf16_f32 %0, %1, %2" : "=v"(r) : "v"(lo), "v"(hi));
  return r;
}
__device__ __forceinline__ void load_lds16(const ushort* g, ushort* l) {
  __builtin_amdgcn_global_load_lds((g_uint*)g, (l_uint*)l, 16, 0, 0);
}

// ---------------- prep: fused fp32->bf16 convert (y=0..2) + W->W^T (y=3..6) ----------------
__global__ void prep(const float* __restrict__ q, const float* __restrict__ k,
                     const float* __restrict__ v,
                     const float* __restrict__ Wq, const float* __restrict__ Wk,
                     const float* __restrict__ Wv, const float* __restrict__ Wo,
                     ushort* __restrict__ qo, ushort* __restrict__ ko, ushort* __restrict__ vo,
                     ushort* __restrict__ WqT, ushort* __restrict__ WkT,
                     ushort* __restrict__ WvT, ushort* __restrict__ WoT) {
  __shared__ float tile[32][33];
  int z = blockIdx.y;
  if (z < 3) {
    const float* s; ushort* d;
    switch (z) {
      case 0: s = q; d = qo; break;
      case 1: s = k; d = ko; break;
      default: s = v; d = vo; break;
    }
    int n4 = (M_ * D_) / 4;
    for (int i = blockIdx.x * blockDim.x + threadIdx.x; i < n4; i += gridDim.x * blockDim.x) {
      float4 x = reinterpret_cast<const float4*>(s)[i];
      ushort4 o;
      o.x = f2bf(x.x); o.y = f2bf(x.y); o.z = f2bf(x.z); o.w = f2bf(x.w);
      reinterpret_cast<ushort4*>(d)[i] = o;
    }
  } else {
    if (blockIdx.x >= 1024) return;
    const float* W; ushort* WT;
    switch (z - 3) {
      case 0: W = Wq; WT = WqT; break;
      case 1: W = Wk; WT = WkT; break;
      case 2: W = Wv; WT = WvT; break;
      default: W = Wo; WT = WoT; break;
    }
    int tx = threadIdx.x & 31, ty = threadIdx.x >> 5;
    int bx = (blockIdx.x & 31) * 32, by = (blockIdx.x >> 5) * 32;
    for (int r = 0; r < 32; r += 8)
      tile[ty + r][tx] = W[(size_t)(by + ty + r) * D_ + bx + tx];
    __syncthreads();
    for (int r = 0; r < 32; r += 8)
      WT[(size_t)(bx + ty + r) * D_ + by + tx] = f2bf(tile[tx][ty + r]);
  }
}

// ---------------- bf16 MFMA GEMM: C[BM,BN] = A[M,K]*Bt[N,K]^T + bias ----------------
// 4 waves as 2x2; wave covers (BM/2) rows x (BN/2) cols.
template <int BF16OUT, int BM, int BN>
__device__ __forceinline__ void gemm_body(const ushort* __restrict__ A,
                                          const ushort* __restrict__ Bt,
                                          const float* __restrict__ bias,
                                          void* __restrict__ Cp,
                                          int bm, int bn, int N, int K) {
  __shared__ ushort Al[BM * 64];
  __shared__ ushort Bl[BN * 64];
  constexpr int MF = BM / 32;   // a-frags / acc rows per wave
  constexpr int NF = BN / 32;   // b-frags / acc cols per wave
  const int tid = threadIdx.x;
  const int wave = tid >> 6, lane = tid & 63;
  const int r0 = lane & 15, kq = lane >> 4;
  const int wr = wave >> 1, wc = wave & 1;
  const int sl = lane >> 3;
  const int sc8 = ((lane & 7) ^ sl) * 8;   // swizzled source col (ushorts)
  f32x4 zero = {0.f, 0.f, 0.f, 0.f};
  f32x4 acc[MF][NF];
#pragma unroll
  for (int m = 0; m < MF; ++m)
#pragma unroll
    for (int n = 0; n < NF; ++n) acc[m][n] = zero;

  for (int kt = 0; kt < K; kt += 64) {
    __syncthreads();
#pragma unroll
    for (int i = 0; i < MF; ++i) {
      int c = wave * MF + i;
      load_lds16(A + (size_t)(bm + c * 8 + sl) * K + kt + sc8, &Al[c * 512]);
    }
#pragma unroll
    for (int i = 0; i < NF; ++i) {
      int c = wave * NF + i;
      load_lds16(Bt + (size_t)(bn + c * 8 + sl) * K + kt + sc8, &Bl[c * 512]);
    }
    __syncthreads();
#pragma unroll
    for (int kk = 0; kk < 2; ++kk) {
      bf16x8 a[MF], b[NF];
#pragma unroll
      for (int m = 0; m < MF; ++m)
        a[m] = *(const bf16x8*)&Al[(wr * (BM / 2) + m * 16 + r0) * 64 + (((kk * 4 + kq) ^ (r0 & 7)) * 8)];
#pragma unroll
      for (int n = 0; n < NF; ++n)
        b[n] = *(const bf16x8*)&Bl[(wc * (BN / 2) + n * 16 + r0) * 64 + (((kk * 4 + kq) ^ (r0 & 7)) * 8)];
#pragma unroll
      for (int m = 0; m < MF; ++m)
#pragma unroll
        for (int n = 0; n < NF; ++n)
          acc[m][n] = __builtin_amdgcn_mfma_f32_16x16x32_bf16(a[m], b[n], acc[m][n], 0, 0, 0);
    }
  }

#pragma unroll
  for (int m = 0; m < MF; ++m) {
#pragma unroll
    for (int n = 0; n < NF; ++n) {
      int col = bn + wc * (BN / 2) + n * 16 + r0;
      float bv = bias[col];
#pragma unroll
      for (int j = 0; j < 4; ++j) {
        int row = bm + wr * (BM / 2) + m * 16 + kq * 4 + j;
        float v = acc[m][n][j] + bv;
        if (BF16OUT) ((ushort*)Cp)[(size_t)row * N + col] = f2bf(v);
        else         ((float*)Cp)[(size_t)row * N + col] = v;
      }
    }
  }
}

__global__ __launch_bounds__(256) void gemm_qkv(const ushort* __restrict__ qa,
                                                const ushort* __restrict__ ka,
                                                const ushort* __restrict__ va,
                                                const ushort* __restrict__ WqT,
                                                const ushort* __restrict__ WkT,
                                                const ushort* __restrict__ WvT,
                                                const float* __restrict__ bq,
                                                const float* __restrict__ bk,
                                                const float* __restrict__ bv,
                                                ushort* __restrict__ Qo,
                                                ushort* __restrict__ Ko,
                                                ushort* __restrict__ Vo) {
  const ushort* A; const ushort* Bt; const float* bias; ushort* C;
  switch (blockIdx.z) {
    case 0: A = qa; Bt = WqT; bias = bq; C = Qo; break;
    case 1: A = ka; Bt = WkT; bias = bk; C = Ko; break;
    default: A = va; Bt = WvT; bias = bv; C = Vo; break;
  }
  gemm_body<1, 64, 128>(A, Bt, bias, C, blockIdx.x * 64, blockIdx.y * 128, D_, D_);
}

__global__ __launch_bounds__(256) void gemm_out(const ushort* __restrict__ A,
                                                const ushort* __restrict__ Bt,
                                                const float* __restrict__ bias,
                                                float* __restrict__ C) {
  gemm_body<0, 64, 128>(A, Bt, bias, C, blockIdx.x * 64, blockIdx.y * 128, D_, D_);
}

// ---------------- fused attention (swapped QK^T: lane owns one q-row) ----------------
// grid 1024: id&63 = (b,h) -> XCD-local K/V panel; qt = 15-(id>>6) heavy-first.
// LDS 40KB -> 4 blocks/CU.
__global__ __launch_bounds__(256) void attn_fused(const ushort* __restrict__ Qb,
                                                  const ushort* __restrict__ Kb,
                                                  const ushort* __restrict__ Vb,
                                                  float* __restrict__ wout,
                                                  ushort* __restrict__ ctx) {
  const int id = blockIdx.x;
  const int bh = id & 63;
  const int b = bh >> 4, h = bh & 15;
  const int qt = NT_ - 1 - (id >> 6);
  const int tid = threadIdx.x, wave = tid >> 6, lane = tid & 63;
  const int r0 = lane & 15, kq = lane >> 4;
  const int sl = lane >> 3;
  const int sc8 = ((lane & 7) ^ sl) * 8;
  __shared__ ushort Kt[2][64 * 64];   // dbuf, both-sides swizzle slot^=(row&7)
  __shared__ ushort Vt[2][64 * 64];   // dbuf, V^T [d][k], col^=(d&7)<<3
  __shared__ ushort Wl[4][16 * 64];   // per-wave P tile [qrow16][k64], 8B-slot swz
  const size_t bh_off = ((size_t)(b * S_)) * D_ + (size_t)h * 64;
  float* wbase = wout + (size_t)bh * S_ * S_;
  const float KSC = 0.18033688011f;   // 0.125 * log2(e)

  // Q fragments straight from global; this lane's q-row = qglob
  const ushort* Qg = Qb + bh_off + (size_t)(qt * 64 + wave * 16 + r0) * D_ + kq * 8;
  bf16x8 qa0 = *(const bf16x8*)Qg;
  bf16x8 qa1 = *(const bf16x8*)(Qg + 32);
  const int qglob = qt * 64 + wave * 16 + r0;

  auto stage_K = [&](int buf, int vb) {
    const ushort* Kg = Kb + bh_off + (size_t)(vb * 64) * D_;
#pragma unroll
    for (int i = 0; i < 2; ++i) {
      int c = wave * 2 + i;
      load_lds16(Kg + (size_t)(c * 8 + sl) * D_ + sc8, &Kt[buf][c * 512]);
    }
  };

  // ---- pass 1: row sums. swapped mfma(K,Q): sc[j] = S[k=jt*16+kq*4+j][q=r0]
  int cur = 0;
  stage_K(0, 0);
  float p0 = 0.f, p1 = 0.f, p2 = 0.f, p3 = 0.f;
  for (int vb = 0; vb <= qt; ++vb) {
    asm volatile("s_waitcnt vmcnt(0)" ::: "memory");
    __builtin_amdgcn_s_barrier();
    if (vb < qt) stage_K(cur ^ 1, vb + 1);
    const bool diag = (vb == qt);
#pragma unroll
    for (int jt = 0; jt < 4; ++jt) {
      int krow = jt * 16 + r0;
      bf16x8 kb0 = *(const bf16x8*)&Kt[cur][krow * 64 + ((kq ^ (r0 & 7)) * 8)];
      bf16x8 kb1 = *(const bf16x8*)&Kt[cur][krow * 64 + (((4 + kq) ^ (r0 & 7)) * 8)];
      f32x4 sc = {0.f, 0.f, 0.f, 0.f};
      sc = __builtin_amdgcn_mfma_f32_16x16x32_bf16(kb0, qa0, sc, 0, 0, 0);
      sc = __builtin_amdgcn_mfma_f32_16x16x32_bf16(kb1, qa1, sc, 0, 0, 0);
      int k0 = vb * 64 + jt * 16 + kq * 4;
      p0 += (diag && k0 + 0 > qglob) ? 0.f : exp2f(sc[0] * KSC);
      p1 += (diag && k0 + 1 > qglob) ? 0.f : exp2f(sc[1] * KSC);
      p2 += (diag && k0 + 2 > qglob) ? 0.f : exp2f(sc[2] * KSC);
      p3 += (diag && k0 + 3 > qglob) ? 0.f : exp2f(sc[3] * KSC);
    }
    cur ^= 1;
  }
  float ssum = (p0 + p1) + (p2 + p3);
  ssum += __shfl_xor(ssum, 16, 64);
  ssum += __shfl_xor(ssum, 32, 64);
  const float rs = 1.f / ssum;   // reciprocal row-sum for q-row qglob

  f32x4 zero = {0.f, 0.f, 0.f, 0.f};
  f32x4 cacc[4];
#pragma unroll
  for (int nt = 0; nt < 4; ++nt) cacc[nt] = zero;

  // ---- pass 2: weights out (from regs) + PV
  __syncthreads();  // pass1 -> pass2 LDS buffer reuse guard
  uint4 vr[2];
  auto vload = [&](int vb) {
    const ushort* Vg = Vb + bh_off + (size_t)(vb * 64) * D_;
    vr[0] = *(const uint4*)&Vg[(size_t)lane * D_ + (size_t)(wave * 2 + 0) * 8];
    vr[1] = *(const uint4*)&Vg[(size_t)lane * D_ + (size_t)(wave * 2 + 1) * 8];
  };
  auto vwrite = [&](int buf) {
#pragma unroll
    for (int it = 0; it < 2; ++it) {
      int seg = wave * 2 + it;
      ushort tmp[8];
      *(uint4*)tmp = vr[it];
#pragma unroll
      for (int e = 0; e < 8; ++e) Vt[buf][(seg * 8 + e) * 64 + (lane ^ (e << 3))] = tmp[e];
    }
  };
  cur = 0;
  stage_K(0, 0);
  vload(0);
  vwrite(0);
  for (int vb = 0; vb <= qt; ++vb) {
    // loads (4) issued before prev tile's 4 weight stores -> vmcnt(4) retires
    // exactly the loads; stores stay in flight across the barrier.
    if (vb == 0) asm volatile("s_waitcnt vmcnt(0) lgkmcnt(0)" ::: "memory");
    else         asm volatile("s_waitcnt vmcnt(4) lgkmcnt(0)" ::: "memory");
    __builtin_amdgcn_s_barrier();
    if (vb < qt) { stage_K(cur ^ 1, vb + 1); vload(vb + 1); }
    const bool diag = (vb == qt);
#pragma unroll
    for (int jt = 0; jt < 4; ++jt) {
      int krow = jt * 16 + r0;
      bf16x8 kb0 = *(const bf16x8*)&Kt[cur][krow * 64 + ((kq ^ (r0 & 7)) * 8)];
      bf16x8 kb1 = *(const bf16x8*)&Kt[cur][krow * 64 + (((4 + kq) ^ (r0 & 7)) * 8)];
      f32x4 sc = {0.f, 0.f, 0.f, 0.f};
      sc = __builtin_amdgcn_mfma_f32_16x16x32_bf16(kb0, qa0, sc, 0, 0, 0);
      sc = __builtin_amdgcn_mfma_f32_16x16x32_bf16(kb1, qa1, sc, 0, 0, 0);
      int k0 = vb * 64 + jt * 16 + kq * 4;
      float e0 = (diag && k0 + 0 > qglob) ? 0.f : exp2f(sc[0] * KSC);
      float e1 = (diag && k0 + 1 > qglob) ? 0.f : exp2f(sc[1] * KSC);
      float e2 = (diag && k0 + 2 > qglob) ? 0.f : exp2f(sc[2] * KSC);
      float e3 = (diag && k0 + 3 > qglob) ? 0.f : exp2f(sc[3] * KSC);
      // packed bf16 quad -> Wl (one ds_write_b64), 8B-slot swizzle s^=(r0&3)<<2
      uint2 pk;
      pk.x = cvtpk(e0, e1);
      pk.y = cvtpk(e2, e3);
      int s = (4 * jt + kq) ^ ((r0 & 3) << 2);
      *(uint2*)&Wl[wave][r0 * 64 + s * 4] = pk;
      // normalized fp32 weights straight from registers (one dwordx4)
      f32x4 o = {e0 * rs, e1 * rs, e2 * rs, e3 * rs};
      *(f32x4*)&wbase[(size_t)qglob * S_ + k0] = o;
    }
    // PV (unnormalized; scaled at the end)
#pragma unroll
    for (int ks = 0; ks < 2; ++ks) {
      int sB = (8 * ks + 2 * kq) ^ ((r0 & 3) << 2);
      bf16x8 af = *(const bf16x8*)&Wl[wave][r0 * 64 + sB * 4];
#pragma unroll
      for (int nt = 0; nt < 4; ++nt) {
        bf16x8 vf = *(const bf16x8*)&Vt[cur][(nt * 16 + r0) * 64 + (((ks * 4 + kq) ^ (r0 & 7)) * 8)];
        cacc[nt] = __builtin_amdgcn_mfma_f32_16x16x32_bf16(af, vf, cacc[nt], 0, 0, 0);
      }
    }
    if (vb < qt) vwrite(cur ^ 1);  // ds_write next V tile (loads landed during compute)
    cur ^= 1;
  }

  // ---- zero the fully-masked region
  {
    int col0 = (qt + 1) * 64;
    int nf4 = (S_ - col0) >> 2;
    int row = tid >> 2, c = tid & 3;
    f32x4 z4 = {0.f, 0.f, 0.f, 0.f};
    float* rp = &wbase[(size_t)(qt * 64 + row) * S_];
    for (int i = c; i < nf4; i += 4) *(f32x4*)&rp[col0 + i * 4] = z4;
  }

  // ---- context out (scaled; rs for q-row kq*4+j fetched from lane kq*4+j)
  {
    float rsj[4];
#pragma unroll
    for (int j = 0; j < 4; ++j) rsj[j] = __shfl(rs, kq * 4 + j, 64);
    ushort* cg = ctx + ((size_t)(b * S_ + qt * 64 + wave * 16 + kq * 4)) * D_ + h * 64;
#pragma unroll
    for (int nt = 0; nt < 4; ++nt)
#pragma unroll
      for (int j = 0; j < 4; ++j)
        cg[(size_t)j * D_ + nt * 16 + r0] = f2bf(cacc[nt][j] * rsj[j]);
  }
}

extern "C" void kernel_launch(void* const* d_in, const int* in_sizes, int n_in,
                              void* d_out, int out_size, void* d_ws, size_t ws_size,
                              hipStream_t stream) {
  const float* q    = (const float*)d_in[0];
  const float* k    = (const float*)d_in[1];
  const float* v    = (const float*)d_in[2];
  const float* Wq   = (const float*)d_in[4];
  const float* bq   = (const float*)d_in[5];
  const float* Wk   = (const float*)d_in[6];
  const float* bk   = (const float*)d_in[7];
  const float* Wv   = (const float*)d_in[8];
  const float* bv   = (const float*)d_in[9];
  const float* Wo   = (const float*)d_in[10];
  const float* bo   = (const float*)d_in[11];

  char* ws = (char*)d_ws;
  const size_t MB = 1024 * 1024;
  ushort* q_bf   = (ushort*)(ws + 0 * MB);
  ushort* k_bf   = (ushort*)(ws + 8 * MB);
  ushort* v_bf   = (ushort*)(ws + 16 * MB);
  ushort* WqT    = (ushort*)(ws + 24 * MB);
  ushort* WkT    = (ushort*)(ws + 26 * MB);
  ushort* WvT    = (ushort*)(ws + 28 * MB);
  ushort* WoT    = (ushort*)(ws + 30 * MB);
  ushort* Q_bf   = (ushort*)(ws + 32 * MB);
  ushort* K_bf   = (ushort*)(ws + 40 * MB);
  ushort* V_bf   = (ushort*)(ws + 48 * MB);
  ushort* ctx_bf = (ushort*)(ws + 56 * MB);

  float* out  = (float*)d_out;
  float* wout = out + (size_t)M_ * D_;

  prep<<<dim3(2048, 7), 256, 0, stream>>>(q, k, v, Wq, Wk, Wv, Wo,
                                          q_bf, k_bf, v_bf, WqT, WkT, WvT, WoT);
  gemm_qkv<<<dim3(M_ / 64, D_ / 128, 3), 256, 0, stream>>>(
      q_bf, k_bf, v_bf, WqT, WkT, WvT, bq, bk, bv, Q_bf, K_bf, V_bf);
  attn_fused<<<dim3(1024), 256, 0, stream>>>(Q_bf, K_bf, V_bf, wout, ctx_bf);
  gemm_out<<<dim3(M_ / 64, D_ / 128), 256, 0, stream>>>(ctx_bf, WoT, bo, out);
}

// Round 13
// 164.415 us; speedup vs baseline: 1.1855x; 1.0061x over previous
//
#include <hip/hip_runtime.h>
#include <hip/hip_bf16.h>

#define B_ 4
#define S_ 1024
#define D_ 1024
#define H_ 16
#define HD_ 64
#define M_ (B_*S_)
#define NT_ (S_/64)   // 16 k/v tiles

typedef __attribute__((ext_vector_type(8))) short bf16x8;
typedef __attribute__((ext_vector_type(8))) unsigned short u16x8;
typedef __attribute__((ext_vector_type(4))) float f32x4;

typedef __attribute__((address_space(1))) const unsigned int g_uint;
typedef __attribute__((address_space(3))) unsigned int l_uint;

__device__ __forceinline__ unsigned short f2bf(float f) {
  unsigned int x = __builtin_bit_cast(unsigned int, f);
  unsigned int r = (x + 0x7fffu + ((x >> 16) & 1u)) >> 16;
  return (unsigned short)r;
}
__device__ __forceinline__ float bf2f(unsigned short u) {
  unsigned int x = ((unsigned int)u) << 16;
  return __builtin_bit_cast(float, x);
}
__device__ __forceinline__ unsigned int cvtpk(float lo, float hi) {
  unsigned int r;
  asm("v_cvt_pk_bf16_f32 %0, %1, %2" : "=v"(r) : "v"(lo), "v"(hi));
  return r;
}
__device__ __forceinline__ void load_lds16(const ushort* g, ushort* l) {
  __builtin_amdgcn_global_load_lds((g_uint*)g, (l_uint*)l, 16, 0, 0);
}

// ---------------- prep: fused fp32->bf16 convert (y=0..2) + W->W^T (y=3..6) ----------------
__global__ void prep(const float* __restrict__ q, const float* __restrict__ k,
                     const float* __restrict__ v,
                     const float* __restrict__ Wq, const float* __restrict__ Wk,
                     const float* __restrict__ Wv, const float* __restrict__ Wo,
                     ushort* __restrict__ qo, ushort* __restrict__ ko, ushort* __restrict__ vo,
                     ushort* __restrict__ WqT, ushort* __restrict__ WkT,
                     ushort* __restrict__ WvT, ushort* __restrict__ WoT) {
  __shared__ float tile[32][33];
  int z = blockIdx.y;
  if (z < 3) {
    const float* s; ushort* d;
    switch (z) {
      case 0: s = q; d = qo; break;
      case 1: s = k; d = ko; break;
      default: s = v; d = vo; break;
    }
    int n4 = (M_ * D_) / 4;
    for (int i = blockIdx.x * blockDim.x + threadIdx.x; i < n4; i += gridDim.x * blockDim.x) {
      float4 x = reinterpret_cast<const float4*>(s)[i];
      ushort4 o;
      o.x = f2bf(x.x); o.y = f2bf(x.y); o.z = f2bf(x.z); o.w = f2bf(x.w);
      reinterpret_cast<ushort4*>(d)[i] = o;
    }
  } else {
    if (blockIdx.x >= 1024) return;
    const float* W; ushort* WT;
    switch (z - 3) {
      case 0: W = Wq; WT = WqT; break;
      case 1: W = Wk; WT = WkT; break;
      case 2: W = Wv; WT = WvT; break;
      default: W = Wo; WT = WoT; break;
    }
    int tx = threadIdx.x & 31, ty = threadIdx.x >> 5;
    int bx = (blockIdx.x & 31) * 32, by = (blockIdx.x >> 5) * 32;
    for (int r = 0; r < 32; r += 8)
      tile[ty + r][tx] = W[(size_t)(by + ty + r) * D_ + bx + tx];
    __syncthreads();
    for (int r = 0; r < 32; r += 8)
      WT[(size_t)(bx + ty + r) * D_ + by + tx] = f2bf(tile[tx][ty + r]);
  }
}

// ---------------- bf16 MFMA GEMM: C[BM,BN] = A[M,K]*Bt[N,K]^T + bias ----------------
// 4 waves as 2x2; wave covers (BM/2) rows x (BN/2) cols.
template <int BF16OUT, int BM, int BN>
__device__ __forceinline__ void gemm_body(const ushort* __restrict__ A,
                                          const ushort* __restrict__ Bt,
                                          const float* __restrict__ bias,
                                          void* __restrict__ Cp,
                                          int bm, int bn, int N, int K) {
  __shared__ ushort Al[BM * 64];
  __shared__ ushort Bl[BN * 64];
  constexpr int MF = BM / 32;   // a-frags / acc rows per wave
  constexpr int NF = BN / 32;   // b-frags / acc cols per wave
  const int tid = threadIdx.x;
  const int wave = tid >> 6, lane = tid & 63;
  const int r0 = lane & 15, kq = lane >> 4;
  const int wr = wave >> 1, wc = wave & 1;
  const int sl = lane >> 3;
  const int sc8 = ((lane & 7) ^ sl) * 8;   // swizzled source col (ushorts)
  f32x4 zero = {0.f, 0.f, 0.f, 0.f};
  f32x4 acc[MF][NF];
#pragma unroll
  for (int m = 0; m < MF; ++m)
#pragma unroll
    for (int n = 0; n < NF; ++n) acc[m][n] = zero;

  for (int kt = 0; kt < K; kt += 64) {
    __syncthreads();
#pragma unroll
    for (int i = 0; i < MF; ++i) {
      int c = wave * MF + i;
      load_lds16(A + (size_t)(bm + c * 8 + sl) * K + kt + sc8, &Al[c * 512]);
    }
#pragma unroll
    for (int i = 0; i < NF; ++i) {
      int c = wave * NF + i;
      load_lds16(Bt + (size_t)(bn + c * 8 + sl) * K + kt + sc8, &Bl[c * 512]);
    }
    __syncthreads();
#pragma unroll
    for (int kk = 0; kk < 2; ++kk) {
      bf16x8 a[MF], b[NF];
#pragma unroll
      for (int m = 0; m < MF; ++m)
        a[m] = *(const bf16x8*)&Al[(wr * (BM / 2) + m * 16 + r0) * 64 + (((kk * 4 + kq) ^ (r0 & 7)) * 8)];
#pragma unroll
      for (int n = 0; n < NF; ++n)
        b[n] = *(const bf16x8*)&Bl[(wc * (BN / 2) + n * 16 + r0) * 64 + (((kk * 4 + kq) ^ (r0 & 7)) * 8)];
#pragma unroll
      for (int m = 0; m < MF; ++m)
#pragma unroll
        for (int n = 0; n < NF; ++n)
          acc[m][n] = __builtin_amdgcn_mfma_f32_16x16x32_bf16(a[m], b[n], acc[m][n], 0, 0, 0);
    }
  }

#pragma unroll
  for (int m = 0; m < MF; ++m) {
#pragma unroll
    for (int n = 0; n < NF; ++n) {
      int col = bn + wc * (BN / 2) + n * 16 + r0;
      float bv = bias[col];
#pragma unroll
      for (int j = 0; j < 4; ++j) {
        int row = bm + wr * (BM / 2) + m * 16 + kq * 4 + j;
        float v = acc[m][n][j] + bv;
        if (BF16OUT) ((ushort*)Cp)[(size_t)row * N + col] = f2bf(v);
        else         ((float*)Cp)[(size_t)row * N + col] = v;
      }
    }
  }
}

__global__ __launch_bounds__(256) void gemm_qkv(const ushort* __restrict__ qa,
                                                const ushort* __restrict__ ka,
                                                const ushort* __restrict__ va,
                                                const ushort* __restrict__ WqT,
                                                const ushort* __restrict__ WkT,
                                                const ushort* __restrict__ WvT,
                                                const float* __restrict__ bq,
                                                const float* __restrict__ bk,
                                                const float* __restrict__ bv,
                                                ushort* __restrict__ Qo,
                                                ushort* __restrict__ Ko,
                                                ushort* __restrict__ Vo) {
  const ushort* A; const ushort* Bt; const float* bias; ushort* C;
  switch (blockIdx.z) {
    case 0: A = qa; Bt = WqT; bias = bq; C = Qo; break;
    case 1: A = ka; Bt = WkT; bias = bk; C = Ko; break;
    default: A = va; Bt = WvT; bias = bv; C = Vo; break;
  }
  gemm_body<1, 64, 128>(A, Bt, bias, C, blockIdx.x * 64, blockIdx.y * 128, D_, D_);
}

__global__ __launch_bounds__(256) void gemm_out(const ushort* __restrict__ A,
                                                const ushort* __restrict__ Bt,
                                                const float* __restrict__ bias,
                                                float* __restrict__ C) {
  gemm_body<0, 64, 64>(A, Bt, bias, C, blockIdx.x * 64, blockIdx.y * 64, D_, D_);
}

// ---------------- fused attention, PAIRED q-tiles (qtA=15-p heavy, qtB=p light) ----
// grid 512: id&63 = (b,h) -> XCD-local K/V panel; p = id>>6 (heavy pairs first).
// Phase 1: pass1(A). Phase 2: pass2(A) + pass1(B) sharing staged K tiles (the
// write-bound A-stores overlap B's register-only QK^T compute in the same wave).
// Phase 3: pass2(B). LDS 40KB.
__global__ __launch_bounds__(256) void attn_fused(const ushort* __restrict__ Qb,
                                                  const ushort* __restrict__ Kb,
                                                  const ushort* __restrict__ Vb,
                                                  float* __restrict__ wout,
                                                  ushort* __restrict__ ctx) {
  const int id = blockIdx.x;
  const int bh = id & 63;
  const int b = bh >> 4, h = bh & 15;
  const int p = id >> 6;
  const int qtA = NT_ - 1 - p;   // 8..15
  const int qtB = p;             // 0..7  (qtB < qtA always)
  const int tid = threadIdx.x, wave = tid >> 6, lane = tid & 63;
  const int r0 = lane & 15, kq = lane >> 4;
  const int sl = lane >> 3;
  const int sc8 = ((lane & 7) ^ sl) * 8;
  __shared__ ushort Kt[2][64 * 64];   // dbuf, both-sides swizzle slot^=(row&7)
  __shared__ ushort Vt[2][64 * 64];   // dbuf, V^T [d][k], col^=(d&7)<<3
  __shared__ ushort Wl[4][16 * 64];   // per-wave P tile, 8B-slot swizzle
  const size_t bh_off = ((size_t)(b * S_)) * D_ + (size_t)h * 64;
  float* wbase = wout + (size_t)bh * S_ * S_;
  const float KSC = 0.18033688011f;   // 0.125 * log2(e)

  // Q fragments for both tiles straight from global
  const ushort* QgA = Qb + bh_off + (size_t)(qtA * 64 + wave * 16 + r0) * D_ + kq * 8;
  bf16x8 qa0A = *(const bf16x8*)QgA;
  bf16x8 qa1A = *(const bf16x8*)(QgA + 32);
  const ushort* QgB = Qb + bh_off + (size_t)(qtB * 64 + wave * 16 + r0) * D_ + kq * 8;
  bf16x8 qa0B = *(const bf16x8*)QgB;
  bf16x8 qa1B = *(const bf16x8*)(QgB + 32);
  const int qgA = qtA * 64 + wave * 16 + r0;
  const int qgB = qtB * 64 + wave * 16 + r0;

  auto stage_K = [&](int buf, int vb) {
    const ushort* Kg = Kb + bh_off + (size_t)(vb * 64) * D_;
#pragma unroll
    for (int i = 0; i < 2; ++i) {
      int c = wave * 2 + i;
      load_lds16(Kg + (size_t)(c * 8 + sl) * D_ + sc8, &Kt[buf][c * 512]);
    }
  };
  uint4 vr[2];
  auto vload = [&](int vb) {
    const ushort* Vg = Vb + bh_off + (size_t)(vb * 64) * D_;
    vr[0] = *(const uint4*)&Vg[(size_t)lane * D_ + (size_t)(wave * 2 + 0) * 8];
    vr[1] = *(const uint4*)&Vg[(size_t)lane * D_ + (size_t)(wave * 2 + 1) * 8];
  };
  auto vwrite = [&](int buf) {
#pragma unroll
    for (int it = 0; it < 2; ++it) {
      int seg = wave * 2 + it;
      ushort tmp[8];
      *(uint4*)tmp = vr[it];
#pragma unroll
      for (int e = 0; e < 8; ++e) Vt[buf][(seg * 8 + e) * 64 + (lane ^ (e << 3))] = tmp[e];
    }
  };

  f32x4 zero = {0.f, 0.f, 0.f, 0.f};

  // ================= phase 1: pass1(A) — row sums for heavy tile =================
  int cur = 0;
  stage_K(0, 0);
  float pA0 = 0.f, pA1 = 0.f, pA2 = 0.f, pA3 = 0.f;
  for (int vb = 0; vb <= qtA; ++vb) {
    asm volatile("s_waitcnt vmcnt(0)" ::: "memory");
    __builtin_amdgcn_s_barrier();
    if (vb < qtA) stage_K(cur ^ 1, vb + 1);
    const bool diag = (vb == qtA);
#pragma unroll
    for (int jt = 0; jt < 4; ++jt) {
      int krow = jt * 16 + r0;
      bf16x8 kb0 = *(const bf16x8*)&Kt[cur][krow * 64 + ((kq ^ (r0 & 7)) * 8)];
      bf16x8 kb1 = *(const bf16x8*)&Kt[cur][krow * 64 + (((4 + kq) ^ (r0 & 7)) * 8)];
      f32x4 sc = {0.f, 0.f, 0.f, 0.f};
      sc = __builtin_amdgcn_mfma_f32_16x16x32_bf16(kb0, qa0A, sc, 0, 0, 0);
      sc = __builtin_amdgcn_mfma_f32_16x16x32_bf16(kb1, qa1A, sc, 0, 0, 0);
      int k0 = vb * 64 + jt * 16 + kq * 4;
      pA0 += (diag && k0 + 0 > qgA) ? 0.f : exp2f(sc[0] * KSC);
      pA1 += (diag && k0 + 1 > qgA) ? 0.f : exp2f(sc[1] * KSC);
      pA2 += (diag && k0 + 2 > qgA) ? 0.f : exp2f(sc[2] * KSC);
      pA3 += (diag && k0 + 3 > qgA) ? 0.f : exp2f(sc[3] * KSC);
    }
    cur ^= 1;
  }
  float ssumA = (pA0 + pA1) + (pA2 + pA3);
  ssumA += __shfl_xor(ssumA, 16, 64);
  ssumA += __shfl_xor(ssumA, 32, 64);
  const float rsA = 1.f / ssumA;

  // ================= phase 2: pass2(A) fused with pass1(B) =================
  f32x4 caccA[4];
#pragma unroll
  for (int nt = 0; nt < 4; ++nt) caccA[nt] = zero;
  float pB0 = 0.f, pB1 = 0.f, pB2 = 0.f, pB3 = 0.f;

  __syncthreads();  // phase1 -> phase2 LDS reuse guard
  cur = 0;
  stage_K(0, 0);
  vload(0);
  vwrite(0);
  for (int vb = 0; vb <= qtA; ++vb) {
    // 4 loads issued before prev iter's 4 weight stores -> vmcnt(4) retires loads
    if (vb == 0) asm volatile("s_waitcnt vmcnt(0) lgkmcnt(0)" ::: "memory");
    else         asm volatile("s_waitcnt vmcnt(4) lgkmcnt(0)" ::: "memory");
    __builtin_amdgcn_s_barrier();
    if (vb < qtA) { stage_K(cur ^ 1, vb + 1); vload(vb + 1); }
    const bool diagA = (vb == qtA);
    const bool doB = (vb <= qtB);
    const bool diagB = (vb == qtB);
#pragma unroll
    for (int jt = 0; jt < 4; ++jt) {
      int krow = jt * 16 + r0;
      bf16x8 kb0 = *(const bf16x8*)&Kt[cur][krow * 64 + ((kq ^ (r0 & 7)) * 8)];
      bf16x8 kb1 = *(const bf16x8*)&Kt[cur][krow * 64 + (((4 + kq) ^ (r0 & 7)) * 8)];
      int k0 = vb * 64 + jt * 16 + kq * 4;
      // ---- A: scores -> e -> Wl (bf16) + normalized fp32 weights store
      f32x4 sc = {0.f, 0.f, 0.f, 0.f};
      sc = __builtin_amdgcn_mfma_f32_16x16x32_bf16(kb0, qa0A, sc, 0, 0, 0);
      sc = __builtin_amdgcn_mfma_f32_16x16x32_bf16(kb1, qa1A, sc, 0, 0, 0);
      float e0 = (diagA && k0 + 0 > qgA) ? 0.f : exp2f(sc[0] * KSC);
      float e1 = (diagA && k0 + 1 > qgA) ? 0.f : exp2f(sc[1] * KSC);
      float e2 = (diagA && k0 + 2 > qgA) ? 0.f : exp2f(sc[2] * KSC);
      float e3 = (diagA && k0 + 3 > qgA) ? 0.f : exp2f(sc[3] * KSC);
      uint2 pk;
      pk.x = cvtpk(e0, e1);
      pk.y = cvtpk(e2, e3);
      int s = (4 * jt + kq) ^ ((r0 & 3) << 2);
      *(uint2*)&Wl[wave][r0 * 64 + s * 4] = pk;
      f32x4 o = {e0 * rsA, e1 * rsA, e2 * rsA, e3 * rsA};
      *(f32x4*)&wbase[(size_t)qgA * S_ + k0] = o;
      // ---- B: pass1 sums ride on the same K fragments (register-only)
      if (doB) {
        f32x4 sb = {0.f, 0.f, 0.f, 0.f};
        sb = __builtin_amdgcn_mfma_f32_16x16x32_bf16(kb0, qa0B, sb, 0, 0, 0);
        sb = __builtin_amdgcn_mfma_f32_16x16x32_bf16(kb1, qa1B, sb, 0, 0, 0);
        pB0 += (diagB && k0 + 0 > qgB) ? 0.f : exp2f(sb[0] * KSC);
        pB1 += (diagB && k0 + 1 > qgB) ? 0.f : exp2f(sb[1] * KSC);
        pB2 += (diagB && k0 + 2 > qgB) ? 0.f : exp2f(sb[2] * KSC);
        pB3 += (diagB && k0 + 3 > qgB) ? 0.f : exp2f(sb[3] * KSC);
      }
    }
    // PV for A (unnormalized; scaled at the end)
#pragma unroll
    for (int ks = 0; ks < 2; ++ks) {
      int sB = (8 * ks + 2 * kq) ^ ((r0 & 3) << 2);
      bf16x8 af = *(const bf16x8*)&Wl[wave][r0 * 64 + sB * 4];
#pragma unroll
      for (int nt = 0; nt < 4; ++nt) {
        bf16x8 vf = *(const bf16x8*)&Vt[cur][(nt * 16 + r0) * 64 + (((ks * 4 + kq) ^ (r0 & 7)) * 8)];
        caccA[nt] = __builtin_amdgcn_mfma_f32_16x16x32_bf16(af, vf, caccA[nt], 0, 0, 0);
      }
    }
    if (vb < qtA) vwrite(cur ^ 1);
    cur ^= 1;
  }
  float ssumB = (pB0 + pB1) + (pB2 + pB3);
  ssumB += __shfl_xor(ssumB, 16, 64);
  ssumB += __shfl_xor(ssumB, 32, 64);
  const float rsB = 1.f / ssumB;

  // ---- A epilogue: zero masked region (empty for qtA=15) + ctx
  {
    int col0 = (qtA + 1) * 64;
    int nf4 = (S_ - col0) >> 2;
    int row = tid >> 2, c = tid & 3;
    f32x4 z4 = {0.f, 0.f, 0.f, 0.f};
    float* rp = &wbase[(size_t)(qtA * 64 + row) * S_];
    for (int i = c; i < nf4; i += 4) *(f32x4*)&rp[col0 + i * 4] = z4;
  }
  {
    float rsj[4];
#pragma unroll
    for (int j = 0; j < 4; ++j) rsj[j] = __shfl(rsA, kq * 4 + j, 64);
    ushort* cg = ctx + ((size_t)(b * S_ + qtA * 64 + wave * 16 + kq * 4)) * D_ + h * 64;
#pragma unroll
    for (int nt = 0; nt < 4; ++nt)
#pragma unroll
      for (int j = 0; j < 4; ++j)
        cg[(size_t)j * D_ + nt * 16 + r0] = f2bf(caccA[nt][j] * rsj[j]);
  }

  // ================= phase 3: pass2(B) =================
  f32x4 caccB[4];
#pragma unroll
  for (int nt = 0; nt < 4; ++nt) caccB[nt] = zero;
  __syncthreads();  // phase2 -> phase3 LDS reuse guard
  cur = 0;
  stage_K(0, 0);
  vload(0);
  vwrite(0);
  for (int vb = 0; vb <= qtB; ++vb) {
    if (vb == 0) asm volatile("s_waitcnt vmcnt(0) lgkmcnt(0)" ::: "memory");
    else         asm volatile("s_waitcnt vmcnt(4) lgkmcnt(0)" ::: "memory");
    __builtin_amdgcn_s_barrier();
    if (vb < qtB) { stage_K(cur ^ 1, vb + 1); vload(vb + 1); }
    const bool diag = (vb == qtB);
#pragma unroll
    for (int jt = 0; jt < 4; ++jt) {
      int krow = jt * 16 + r0;
      bf16x8 kb0 = *(const bf16x8*)&Kt[cur][krow * 64 + ((kq ^ (r0 & 7)) * 8)];
      bf16x8 kb1 = *(const bf16x8*)&Kt[cur][krow * 64 + (((4 + kq) ^ (r0 & 7)) * 8)];
      f32x4 sc = {0.f, 0.f, 0.f, 0.f};
      sc = __builtin_amdgcn_mfma_f32_16x16x32_bf16(kb0, qa0B, sc, 0, 0, 0);
      sc = __builtin_amdgcn_mfma_f32_16x16x32_bf16(kb1, qa1B, sc, 0, 0, 0);
      int k0 = vb * 64 + jt * 16 + kq * 4;
      float e0 = (diag && k0 + 0 > qgB) ? 0.f : exp2f(sc[0] * KSC);
      float e1 = (diag && k0 + 1 > qgB) ? 0.f : exp2f(sc[1] * KSC);
      float e2 = (diag && k0 + 2 > qgB) ? 0.f : exp2f(sc[2] * KSC);
      float e3 = (diag && k0 + 3 > qgB) ? 0.f : exp2f(sc[3] * KSC);
      uint2 pk;
      pk.x = cvtpk(e0, e1);
      pk.y = cvtpk(e2, e3);
      int s = (4 * jt + kq) ^ ((r0 & 3) << 2);
      *(uint2*)&Wl[wave][r0 * 64 + s * 4] = pk;
      f32x4 o = {e0 * rsB, e1 * rsB, e2 * rsB, e3 * rsB};
      *(f32x4*)&wbase[(size_t)qgB * S_ + k0] = o;
    }
#pragma unroll
    for (int ks = 0; ks < 2; ++ks) {
      int sB = (8 * ks + 2 * kq) ^ ((r0 & 3) << 2);
      bf16x8 af = *(const bf16x8*)&Wl[wave][r0 * 64 + sB * 4];
#pragma unroll
      for (int nt = 0; nt < 4; ++nt) {
        bf16x8 vf = *(const bf16x8*)&Vt[cur][(nt * 16 + r0) * 64 + (((ks * 4 + kq) ^ (r0 & 7)) * 8)];
        caccB[nt] = __builtin_amdgcn_mfma_f32_16x16x32_bf16(af, vf, caccB[nt], 0, 0, 0);
      }
    }
    if (vb < qtB) vwrite(cur ^ 1);
    cur ^= 1;
  }

  // ---- B epilogue: zero masked region (large) + ctx
  {
    int col0 = (qtB + 1) * 64;
    int nf4 = (S_ - col0) >> 2;
    int row = tid >> 2, c = tid & 3;
    f32x4 z4 = {0.f, 0.f, 0.f, 0.f};
    float* rp = &wbase[(size_t)(qtB * 64 + row) * S_];
    for (int i = c; i < nf4; i += 4) *(f32x4*)&rp[col0 + i * 4] = z4;
  }
  {
    float rsj[4];
#pragma unroll
    for (int j = 0; j < 4; ++j) rsj[j] = __shfl(rsB, kq * 4 + j, 64);
    ushort* cg = ctx + ((size_t)(b * S_ + qtB * 64 + wave * 16 + kq * 4)) * D_ + h * 64;
#pragma unroll
    for (int nt = 0; nt < 4; ++nt)
#pragma unroll
      for (int j = 0; j < 4; ++j)
        cg[(size_t)j * D_ + nt * 16 + r0] = f2bf(caccB[nt][j] * rsj[j]);
  }
}

extern "C" void kernel_launch(void* const* d_in, const int* in_sizes, int n_in,
                              void* d_out, int out_size, void* d_ws, size_t ws_size,
                              hipStream_t stream) {
  const float* q    = (const float*)d_in[0];
  const float* k    = (const float*)d_in[1];
  const float* v    = (const float*)d_in[2];
  const float* Wq   = (const float*)d_in[4];
  const float* bq   = (const float*)d_in[5];
  const float* Wk   = (const float*)d_in[6];
  const float* bk   = (const float*)d_in[7];
  const float* Wv   = (const float*)d_in[8];
  const float* bv   = (const float*)d_in[9];
  const float* Wo   = (const float*)d_in[10];
  const float* bo   = (const float*)d_in[11];

  char* ws = (char*)d_ws;
  const size_t MB = 1024 * 1024;
  ushort* q_bf   = (ushort*)(ws + 0 * MB);
  ushort* k_bf   = (ushort*)(ws + 8 * MB);
  ushort* v_bf   = (ushort*)(ws + 16 * MB);
  ushort* WqT    = (ushort*)(ws + 24 * MB);
  ushort* WkT    = (ushort*)(ws + 26 * MB);
  ushort* WvT    = (ushort*)(ws + 28 * MB);
  ushort* WoT    = (ushort*)(ws + 30 * MB);
  ushort* Q_bf   = (ushort*)(ws + 32 * MB);
  ushort* K_bf   = (ushort*)(ws + 40 * MB);
  ushort* V_bf   = (ushort*)(ws + 48 * MB);
  ushort* ctx_bf = (ushort*)(ws + 56 * MB);

  float* out  = (float*)d_out;
  float* wout = out + (size_t)M_ * D_;

  prep<<<dim3(2048, 7), 256, 0, stream>>>(q, k, v, Wq, Wk, Wv, Wo,
                                          q_bf, k_bf, v_bf, WqT, WkT, WvT, WoT);
  gemm_qkv<<<dim3(M_ / 64, D_ / 128, 3), 256, 0, stream>>>(
      q_bf, k_bf, v_bf, WqT, WkT, WvT, bq, bk, bv, Q_bf, K_bf, V_bf);
  attn_fused<<<dim3(512), 256, 0, stream>>>(Q_bf, K_bf, V_bf, wout, ctx_bf);
  gemm_out<<<dim3(M_ / 64, D_ / 64), 256, 0, stream>>>(ctx_bf, WoT, bo, out);
}